// Round 1
// baseline (280.952 us; speedup 1.0000x reference)
//
#include <hip/hip_runtime.h>

typedef unsigned short u16;
typedef u16  u16x8 __attribute__((ext_vector_type(8)));
typedef u16  u16x4 __attribute__((ext_vector_type(4)));
typedef float f32x4 __attribute__((ext_vector_type(4)));
typedef __bf16 bf16x8 __attribute__((ext_vector_type(8)));

// Problem constants
#define BATCH 4
#define PATCH 8
#define SEQ   512
#define DIM   512
#define HEADS 8
#define DHEAD 64
#define M_ROWS (BATCH*PATCH*SEQ)   // 16384

// fp32 -> bf16 round-to-nearest-even (inputs are finite; no NaN handling needed)
__device__ __forceinline__ u16 f2b(float f) {
  unsigned int x = __builtin_bit_cast(unsigned int, f);
  unsigned int r = (x + 0x7fffu + ((x >> 16) & 1u)) >> 16;
  return (u16)r;
}

// ---------------------------------------------------------------------------
// Kernel 0: transpose + convert weights fp32 [K,N] -> bf16 [N,K] (B^T layout)
// ---------------------------------------------------------------------------
__global__ __launch_bounds__(256) void wtrans(const float* __restrict__ Wq,
                                              const float* __restrict__ Wk,
                                              const float* __restrict__ Wv,
                                              const float* __restrict__ Wo,
                                              u16* __restrict__ out) {
  __shared__ float tile[32][33];
  const int tid = threadIdx.x;
  const int tx = tid & 31, ty = tid >> 5;         // 32 x 8
  const int z = blockIdx.z;
  const float* W = (z == 0) ? Wq : (z == 1) ? Wk : (z == 2) ? Wv : Wo;
  const int n0 = blockIdx.x * 32;                 // input col tile
  const int k0 = blockIdx.y * 32;                 // input row tile
#pragma unroll
  for (int i = 0; i < 4; i++) {
    int r = ty + i * 8;
    tile[r][tx] = W[(k0 + r) * DIM + n0 + tx];    // coalesced read
  }
  __syncthreads();
  u16* o = out + (size_t)z * DIM * DIM;
#pragma unroll
  for (int i = 0; i < 4; i++) {
    int r = ty + i * 8;
    o[(n0 + r) * DIM + k0 + tx] = f2b(tile[tx][r]); // coalesced write
  }
}

// ---------------------------------------------------------------------------
// Kernel 1: projection GEMM  C[M,512] = A[M,512](fp32) @ W (Bt = bf16 [N][K])
// 128x128 tile, BK=32, 256 threads = 4 waves, each wave 64x64 via 4x4 MFMA
// ---------------------------------------------------------------------------
__global__ __launch_bounds__(256) void gemm_proj(const float* __restrict__ A,
                                                 const u16* __restrict__ Bt,
                                                 u16* __restrict__ C) {
  __shared__ u16 As[128 * 40];   // [m][k], pitch 40 (2-way bank conflicts only)
  __shared__ u16 Bs[128 * 40];   // [n][k]
  const int tid = threadIdx.x;
  const int lane = tid & 63;
  const int w = tid >> 6;
  const int l15 = lane & 15;
  const int quad = lane >> 4;
  const int gm = blockIdx.y * 128;
  const int gn = blockIdx.x * 128;
  const int wr = (w >> 1) * 64, wc = (w & 1) * 64;

  f32x4 acc[4][4] = {};

  for (int k0 = 0; k0 < DIM; k0 += 32) {
    __syncthreads();
    // stage A tile 128x32 fp32 -> bf16
#pragma unroll
    for (int i = 0; i < 4; i++) {
      int idx = tid + i * 256;
      int row = idx >> 3, c = idx & 7;
      const float4 av = *reinterpret_cast<const float4*>(&A[(gm + row) * DIM + k0 + c * 4]);
      u16x4 t; t[0] = f2b(av.x); t[1] = f2b(av.y); t[2] = f2b(av.z); t[3] = f2b(av.w);
      *reinterpret_cast<u16x4*>(&As[row * 40 + c * 4]) = t;
    }
    // stage B tile 128(n) x 32(k) bf16
#pragma unroll
    for (int i = 0; i < 2; i++) {
      int idx = tid + i * 256;
      int nrow = idx >> 2, c = idx & 3;
      u16x8 bv = *reinterpret_cast<const u16x8*>(&Bt[(gn + nrow) * DIM + k0 + c * 8]);
      *reinterpret_cast<u16x8*>(&Bs[nrow * 40 + c * 8]) = bv;
    }
    __syncthreads();

    bf16x8 af[4], bf[4];
#pragma unroll
    for (int mt = 0; mt < 4; mt++)
      af[mt] = *reinterpret_cast<const bf16x8*>(&As[(wr + mt * 16 + l15) * 40 + quad * 8]);
#pragma unroll
    for (int nt = 0; nt < 4; nt++)
      bf[nt] = *reinterpret_cast<const bf16x8*>(&Bs[(wc + nt * 16 + l15) * 40 + quad * 8]);
#pragma unroll
    for (int mt = 0; mt < 4; mt++)
#pragma unroll
      for (int nt = 0; nt < 4; nt++)
        acc[mt][nt] = __builtin_amdgcn_mfma_f32_16x16x32_bf16(af[mt], bf[nt], acc[mt][nt], 0, 0, 0);
  }

  // epilogue: bf16 out, [M,512] layout
#pragma unroll
  for (int mt = 0; mt < 4; mt++)
#pragma unroll
    for (int nt = 0; nt < 4; nt++)
#pragma unroll
      for (int r = 0; r < 4; r++)
        C[(gm + wr + mt * 16 + quad * 4 + r) * DIM + gn + wc + nt * 16 + l15] = f2b(acc[mt][nt][r]);
}

// ---------------------------------------------------------------------------
// Kernel 2: flash attention per (b,p,h, 64-row Q tile).
// Q/K/V bf16 in [M,512] layout (head h occupies cols h*64..h*64+63).
// ---------------------------------------------------------------------------
__global__ __launch_bounds__(256) void attn(const u16* __restrict__ Qb,
                                            const u16* __restrict__ Kb,
                                            const u16* __restrict__ Vb,
                                            u16* __restrict__ Ob) {
  __shared__ u16 Qs[64 * 72];        // [qrow][d]   pitch 72
  __shared__ u16 Ks[128 * 72];       // [key][d]    pitch 72
  __shared__ u16 Vt[64 * 136];       // [d][key]    pitch 136 (transposed)
  __shared__ u16 Pl[4][16 * 136];    // per-wave P  [qrow][key] pitch 136

  const int tid = threadIdx.x;
  const int lane = tid & 63;
  const int w = tid >> 6;
  const int l15 = lane & 15;
  const int quad = lane >> 4;

  const int bid = blockIdx.x;
  const int qt = bid & 7;            // 8 Q tiles of 64 rows
  const int bhp = bid >> 3;
  const int h = bhp & 7;
  const int bp = bhp >> 3;           // 0..31
  const int qrow0 = bp * SEQ + qt * 64;
  const int col0 = h * DHEAD;

  // stage Q tile 64x64
#pragma unroll
  for (int i = 0; i < 2; i++) {
    int idx = tid + i * 256;
    int row = idx >> 3, c = idx & 7;
    u16x8 v = *reinterpret_cast<const u16x8*>(&Qb[(qrow0 + row) * DIM + col0 + c * 8]);
    *reinterpret_cast<u16x8*>(&Qs[row * 72 + c * 8]) = v;
  }
  __syncthreads();

  bf16x8 qf[2];
#pragma unroll
  for (int ks = 0; ks < 2; ks++)
    qf[ks] = *reinterpret_cast<const bf16x8*>(&Qs[(w * 16 + l15) * 72 + ks * 32 + quad * 8]);

  float m_[4], l_[4];
  f32x4 o[4] = {};
#pragma unroll
  for (int r = 0; r < 4; r++) { m_[r] = -1e30f; l_[r] = 0.0f; }

  for (int j = 0; j < 4; j++) {
    __syncthreads();
    // stage K_j 128x64
#pragma unroll
    for (int i = 0; i < 4; i++) {
      int idx = tid + i * 256;
      int row = idx >> 3, c = idx & 7;
      u16x8 v = *reinterpret_cast<const u16x8*>(&Kb[(bp * SEQ + j * 128 + row) * DIM + col0 + c * 8]);
      *reinterpret_cast<u16x8*>(&Ks[row * 72 + c * 8]) = v;
    }
    // stage V_j transposed -> Vt[d][key]
#pragma unroll
    for (int i = 0; i < 4; i++) {
      int idx = tid + i * 256;
      int key = idx >> 3, c = idx & 7;
      u16x8 v = *reinterpret_cast<const u16x8*>(&Vb[(bp * SEQ + j * 128 + key) * DIM + col0 + c * 8]);
#pragma unroll
      for (int e = 0; e < 8; e++) Vt[(c * 8 + e) * 136 + key] = v[e];
    }
    __syncthreads();

    // S = Q K^T  (wave: 16 q-rows x 128 keys)
    f32x4 s[8];
#pragma unroll
    for (int ct = 0; ct < 8; ct++) {
      f32x4 z = {};
#pragma unroll
      for (int ks = 0; ks < 2; ks++) {
        bf16x8 b = *reinterpret_cast<const bf16x8*>(&Ks[(ct * 16 + l15) * 72 + ks * 32 + quad * 8]);
        z = __builtin_amdgcn_mfma_f32_16x16x32_bf16(qf[ks], b, z, 0, 0, 0);
      }
      s[ct] = z * 0.125f;   // SCALE = 64^-0.5
    }

    // online softmax per row (row = quad*4 + r; spans 16 lanes of the quad)
#pragma unroll
    for (int r = 0; r < 4; r++) {
      float pm = s[0][r];
#pragma unroll
      for (int ct = 1; ct < 8; ct++) pm = fmaxf(pm, s[ct][r]);
#pragma unroll
      for (int mask = 1; mask < 16; mask <<= 1) pm = fmaxf(pm, __shfl_xor(pm, mask));
      float mn = fmaxf(m_[r], pm);
      float alpha = __expf(m_[r] - mn);
      float rs = 0.0f;
#pragma unroll
      for (int ct = 0; ct < 8; ct++) {
        float pv = __expf(s[ct][r] - mn);
        s[ct][r] = pv;
        rs += pv;
      }
#pragma unroll
      for (int mask = 1; mask < 16; mask <<= 1) rs += __shfl_xor(rs, mask);
      l_[r] = l_[r] * alpha + rs;
      m_[r] = mn;
#pragma unroll
      for (int nt = 0; nt < 4; nt++) o[nt][r] *= alpha;
    }

    // P (C-layout) -> LDS -> A-layout for PV
#pragma unroll
    for (int ct = 0; ct < 8; ct++)
#pragma unroll
      for (int r = 0; r < 4; r++)
        Pl[w][(quad * 4 + r) * 136 + ct * 16 + l15] = f2b(s[ct][r]);

#pragma unroll
    for (int ks2 = 0; ks2 < 4; ks2++) {
      bf16x8 a = *reinterpret_cast<const bf16x8*>(&Pl[w][l15 * 136 + ks2 * 32 + quad * 8]);
#pragma unroll
      for (int nt = 0; nt < 4; nt++) {
        bf16x8 b = *reinterpret_cast<const bf16x8*>(&Vt[(nt * 16 + l15) * 136 + ks2 * 32 + quad * 8]);
        o[nt] = __builtin_amdgcn_mfma_f32_16x16x32_bf16(a, b, o[nt], 0, 0, 0);
      }
    }
  }

  // normalize and write attn output (bf16, [M,512] layout)
#pragma unroll
  for (int r = 0; r < 4; r++) {
    float inv = 1.0f / l_[r];
#pragma unroll
    for (int nt = 0; nt < 4; nt++)
      Ob[(qrow0 + w * 16 + quad * 4 + r) * DIM + col0 + nt * 16 + l15] = f2b(o[nt][r] * inv);
  }
}

// ---------------------------------------------------------------------------
// Kernel 3: output GEMM  out[M,512](fp32) = Ab[M,512](bf16) @ Wo (Bt) + bias
// ---------------------------------------------------------------------------
__global__ __launch_bounds__(256) void gemm_out(const u16* __restrict__ Ab,
                                                const u16* __restrict__ Bt,
                                                const float* __restrict__ bias,
                                                float* __restrict__ C) {
  __shared__ u16 As[128 * 40];
  __shared__ u16 Bs[128 * 40];
  const int tid = threadIdx.x;
  const int lane = tid & 63;
  const int w = tid >> 6;
  const int l15 = lane & 15;
  const int quad = lane >> 4;
  const int gm = blockIdx.y * 128;
  const int gn = blockIdx.x * 128;
  const int wr = (w >> 1) * 64, wc = (w & 1) * 64;

  f32x4 acc[4][4] = {};

  for (int k0 = 0; k0 < DIM; k0 += 32) {
    __syncthreads();
#pragma unroll
    for (int i = 0; i < 2; i++) {
      int idx = tid + i * 256;
      int row = idx >> 2, c = idx & 3;
      u16x8 av = *reinterpret_cast<const u16x8*>(&Ab[(gm + row) * DIM + k0 + c * 8]);
      *reinterpret_cast<u16x8*>(&As[row * 40 + c * 8]) = av;
    }
#pragma unroll
    for (int i = 0; i < 2; i++) {
      int idx = tid + i * 256;
      int nrow = idx >> 2, c = idx & 3;
      u16x8 bv = *reinterpret_cast<const u16x8*>(&Bt[(gn + nrow) * DIM + k0 + c * 8]);
      *reinterpret_cast<u16x8*>(&Bs[nrow * 40 + c * 8]) = bv;
    }
    __syncthreads();

    bf16x8 af[4], bf[4];
#pragma unroll
    for (int mt = 0; mt < 4; mt++)
      af[mt] = *reinterpret_cast<const bf16x8*>(&As[(wr + mt * 16 + l15) * 40 + quad * 8]);
#pragma unroll
    for (int nt = 0; nt < 4; nt++)
      bf[nt] = *reinterpret_cast<const bf16x8*>(&Bs[(wc + nt * 16 + l15) * 40 + quad * 8]);
#pragma unroll
    for (int mt = 0; mt < 4; mt++)
#pragma unroll
      for (int nt = 0; nt < 4; nt++)
        acc[mt][nt] = __builtin_amdgcn_mfma_f32_16x16x32_bf16(af[mt], bf[nt], acc[mt][nt], 0, 0, 0);
  }

#pragma unroll
  for (int mt = 0; mt < 4; mt++)
#pragma unroll
    for (int nt = 0; nt < 4; nt++) {
      float bcol = bias[gn + wc + nt * 16 + l15];
#pragma unroll
      for (int r = 0; r < 4; r++)
        C[(gm + wr + mt * 16 + quad * 4 + r) * DIM + gn + wc + nt * 16 + l15] = acc[mt][nt][r] + bcol;
    }
}

// ---------------------------------------------------------------------------
extern "C" void kernel_launch(void* const* d_in, const int* in_sizes, int n_in,
                              void* d_out, int out_size, void* d_ws, size_t ws_size,
                              hipStream_t stream) {
  const float* q_in  = (const float*)d_in[0];
  const float* kv_in = (const float*)d_in[1];
  const float* Wq    = (const float*)d_in[2];
  const float* Wk    = (const float*)d_in[3];
  const float* Wv    = (const float*)d_in[4];
  const float* Wo    = (const float*)d_in[5];
  const float* bo    = (const float*)d_in[6];
  float* out = (float*)d_out;

  u16* ws = (u16*)d_ws;
  u16* Wqt = ws;                       // 512*512 each
  u16* Wkt = ws + 262144;
  u16* Wvt = ws + 524288;
  u16* Wot = ws + 786432;
  u16* Qb  = ws + 1048576;             // M*512 each
  u16* Kb  = Qb + (size_t)M_ROWS * DIM;
  u16* Vb  = Kb + (size_t)M_ROWS * DIM;
  u16* Ob  = Vb + (size_t)M_ROWS * DIM;

  // 0) weights: fp32 [K,N] -> bf16 [N,K]
  wtrans<<<dim3(16, 16, 4), 256, 0, stream>>>(Wq, Wk, Wv, Wo, ws);
  // 1) projections
  gemm_proj<<<dim3(4, 128), 256, 0, stream>>>(q_in,  Wqt, Qb);
  gemm_proj<<<dim3(4, 128), 256, 0, stream>>>(kv_in, Wkt, Kb);
  gemm_proj<<<dim3(4, 128), 256, 0, stream>>>(kv_in, Wvt, Vb);
  // 2) attention
  attn<<<dim3(2048), 256, 0, stream>>>(Qb, Kb, Vb, Ob);
  // 3) output projection + bias
  gemm_out<<<dim3(4, 128), 256, 0, stream>>>(Ob, Wot, bo, out);
}

// Round 2
// 254.172 us; speedup vs baseline: 1.1054x; 1.1054x over previous
//
#include <hip/hip_runtime.h>

typedef unsigned short u16;
typedef u16  u16x8 __attribute__((ext_vector_type(8)));
typedef u16  u16x4 __attribute__((ext_vector_type(4)));
typedef float f32x4 __attribute__((ext_vector_type(4)));
typedef __bf16 bf16x8 __attribute__((ext_vector_type(8)));

#define SEQ   512
#define DIM   512
#define DHEAD 64
#define M_ROWS 16384   // 4*8*512

__device__ __forceinline__ u16 f2b(float f) {
  unsigned int x = __builtin_bit_cast(unsigned int, f);
  return (u16)((x + 0x7fffu + ((x >> 16) & 1u)) >> 16);
}

// ---------------------------------------------------------------------------
// Kernel 0: transpose + convert weights fp32 [K,N] -> bf16 [N,K]
// ---------------------------------------------------------------------------
__global__ __launch_bounds__(256) void wtrans(const float* __restrict__ Wq,
                                              const float* __restrict__ Wk,
                                              const float* __restrict__ Wv,
                                              const float* __restrict__ Wo,
                                              u16* __restrict__ out) {
  __shared__ float tile[32][33];
  const int tid = threadIdx.x;
  const int tx = tid & 31, ty = tid >> 5;
  const int z = blockIdx.z;
  const float* W = (z == 0) ? Wq : (z == 1) ? Wk : (z == 2) ? Wv : Wo;
  const int n0 = blockIdx.x * 32;
  const int k0 = blockIdx.y * 32;
#pragma unroll
  for (int i = 0; i < 4; i++) {
    int r = ty + i * 8;
    tile[r][tx] = W[(k0 + r) * DIM + n0 + tx];
  }
  __syncthreads();
  u16* o = out + (size_t)z * DIM * DIM;
#pragma unroll
  for (int i = 0; i < 4; i++) {
    int r = ty + i * 8;
    o[(n0 + r) * DIM + k0 + tx] = f2b(tile[tx][r]);
  }
}

// ---------------------------------------------------------------------------
// Kernel 1: fused Q/K/V^T projection GEMM (grid.z = 0,1,2)
//  z=0: Qb[M,512]  = q_in(fp32)  @ Wq   (A=q_in fp32, Bt=Wqt bf16)
//  z=1: Kb[M,512]  = kv_in(fp32) @ Wk
//  z=2: Vt[512,M]  = (kv_in @ Wv)^T = Wv^T · kv^T  (A=Wvt bf16, Bt=kv fp32)
// 128x128 tile, BK=32, 4 waves, each 64x64 via 4x4 MFMA 16x16x32 bf16
// ---------------------------------------------------------------------------
__global__ __launch_bounds__(256) void gemm_qkv(const float* __restrict__ q_in,
                                                const float* __restrict__ kv_in,
                                                const u16* __restrict__ Wqt,
                                                const u16* __restrict__ Wkt,
                                                const u16* __restrict__ Wvt,
                                                u16* __restrict__ Qb,
                                                u16* __restrict__ Kb,
                                                u16* __restrict__ Vt) {
  __shared__ u16 As[128 * 40];
  __shared__ u16 Bs[128 * 40];
  const int tid = threadIdx.x;
  const int lane = tid & 63;
  const int w = tid >> 6;
  const int l15 = lane & 15;
  const int quad = lane >> 4;
  const int z = blockIdx.z;
  const int wr = (w >> 1) * 64, wc = (w & 1) * 64;

  int gm, gn;
  const float* Af = nullptr; const u16* Ab = nullptr;
  const float* Bf = nullptr; const u16* Bb = nullptr;
  if (z < 2) {
    gm = blockIdx.y * 128; gn = blockIdx.x * 128;
    Af = (z == 0) ? q_in : kv_in;
    Bb = (z == 0) ? Wqt : Wkt;
  } else {
    gm = blockIdx.x * 128; gn = blockIdx.y * 128;
    Ab = Wvt; Bf = kv_in;
  }

  f32x4 acc[4][4] = {};

  for (int k0 = 0; k0 < DIM; k0 += 32) {
    __syncthreads();
    if (z < 2) {
      // A: fp32 -> bf16 staging, 128x32
#pragma unroll
      for (int i = 0; i < 4; i++) {
        int idx = tid + i * 256;
        int row = idx >> 3, c = idx & 7;
        const float4 av = *reinterpret_cast<const float4*>(&Af[(gm + row) * DIM + k0 + c * 4]);
        u16x4 t; t[0] = f2b(av.x); t[1] = f2b(av.y); t[2] = f2b(av.z); t[3] = f2b(av.w);
        *reinterpret_cast<u16x4*>(&As[row * 40 + c * 4]) = t;
      }
      // B: bf16 staging, 128x32
#pragma unroll
      for (int i = 0; i < 2; i++) {
        int idx = tid + i * 256;
        int nrow = idx >> 2, c = idx & 3;
        u16x8 bv = *reinterpret_cast<const u16x8*>(&Bb[(gn + nrow) * DIM + k0 + c * 8]);
        *reinterpret_cast<u16x8*>(&Bs[nrow * 40 + c * 8]) = bv;
      }
    } else {
      // A: bf16 (Wvt)
#pragma unroll
      for (int i = 0; i < 2; i++) {
        int idx = tid + i * 256;
        int row = idx >> 2, c = idx & 3;
        u16x8 av = *reinterpret_cast<const u16x8*>(&Ab[(gm + row) * DIM + k0 + c * 8]);
        *reinterpret_cast<u16x8*>(&As[row * 40 + c * 8]) = av;
      }
      // B: fp32 (kv rows) -> bf16
#pragma unroll
      for (int i = 0; i < 4; i++) {
        int idx = tid + i * 256;
        int row = idx >> 3, c = idx & 7;
        const float4 bv = *reinterpret_cast<const float4*>(&Bf[(gn + row) * DIM + k0 + c * 4]);
        u16x4 t; t[0] = f2b(bv.x); t[1] = f2b(bv.y); t[2] = f2b(bv.z); t[3] = f2b(bv.w);
        *reinterpret_cast<u16x4*>(&Bs[row * 40 + c * 4]) = t;
      }
    }
    __syncthreads();

    bf16x8 af[4], bf[4];
#pragma unroll
    for (int mt = 0; mt < 4; mt++)
      af[mt] = *reinterpret_cast<const bf16x8*>(&As[(wr + mt * 16 + l15) * 40 + quad * 8]);
#pragma unroll
    for (int nt = 0; nt < 4; nt++)
      bf[nt] = *reinterpret_cast<const bf16x8*>(&Bs[(wc + nt * 16 + l15) * 40 + quad * 8]);
#pragma unroll
    for (int mt = 0; mt < 4; mt++)
#pragma unroll
      for (int nt = 0; nt < 4; nt++)
        acc[mt][nt] = __builtin_amdgcn_mfma_f32_16x16x32_bf16(af[mt], bf[nt], acc[mt][nt], 0, 0, 0);
  }

  if (z < 2) {
    u16* C = (z == 0) ? Qb : Kb;
#pragma unroll
    for (int mt = 0; mt < 4; mt++)
#pragma unroll
      for (int nt = 0; nt < 4; nt++)
#pragma unroll
        for (int r = 0; r < 4; r++)
          C[(gm + wr + mt * 16 + quad * 4 + r) * DIM + gn + wc + nt * 16 + l15] = f2b(acc[mt][nt][r]);
  } else {
#pragma unroll
    for (int mt = 0; mt < 4; mt++)
#pragma unroll
      for (int nt = 0; nt < 4; nt++)
#pragma unroll
        for (int r = 0; r < 4; r++)
          Vt[(size_t)(gm + wr + mt * 16 + quad * 4 + r) * M_ROWS + gn + wc + nt * 16 + l15] = f2b(acc[mt][nt][r]);
  }
}

// ---------------------------------------------------------------------------
// Kernel 2: flash attention. Block = (b,p,h, 64 q-rows); 64-key tiles x8.
// S^T = K·Q^T so P^T exits in C-layout (col=q=l15); softmax mostly in-reg;
// P^T -> per-wave LDS (b64 packed) -> A-frag b128; V^T staged from global Vt.
// All LDS pitches 72 u16 (16B-aligned rows, conflict-free b128).
// ---------------------------------------------------------------------------
__global__ __launch_bounds__(256) void attn(const u16* __restrict__ Qb,
                                            const u16* __restrict__ Kb,
                                            const u16* __restrict__ Vtg,
                                            u16* __restrict__ Ob) {
  __shared__ u16 Qs[64 * 72];        // [q][d]
  __shared__ u16 Ks[64 * 72];        // [key][d]
  __shared__ u16 Vs[64 * 72];        // [d][key]  (from pre-transposed global V^T)
  __shared__ u16 Pq[4][16 * 72];     // per-wave P [q][key]

  const int tid = threadIdx.x;
  const int lane = tid & 63;
  const int w = tid >> 6;
  const int l15 = lane & 15;
  const int quad = lane >> 4;

  const int bid = blockIdx.x;
  const int qt = bid & 7;
  const int bhp = bid >> 3;
  const int h = bhp & 7;
  const int bp = bhp >> 3;
  const int qrow0 = bp * SEQ + qt * 64;
  const int col0 = h * DHEAD;

  // stage Q tile 64x64 once
#pragma unroll
  for (int i = 0; i < 2; i++) {
    int idx = tid + i * 256;
    int row = idx >> 3, c = idx & 7;
    u16x8 v = *reinterpret_cast<const u16x8*>(&Qb[(qrow0 + row) * DIM + col0 + c * 8]);
    *reinterpret_cast<u16x8*>(&Qs[row * 72 + c * 8]) = v;
  }
  __syncthreads();

  bf16x8 qf[2];
#pragma unroll
  for (int kd = 0; kd < 2; kd++)
    qf[kd] = *reinterpret_cast<const bf16x8*>(&Qs[(w * 16 + l15) * 72 + kd * 32 + quad * 8]);

  float m_ = -1e30f, l_ = 0.0f;
  f32x4 o[4] = {};

  for (int j = 0; j < 8; j++) {
    __syncthreads();
    // stage K tile 64 keys x 64 d
#pragma unroll
    for (int i = 0; i < 2; i++) {
      int idx = tid + i * 256;
      int row = idx >> 3, c = idx & 7;
      u16x8 v = *reinterpret_cast<const u16x8*>(&Kb[(bp * SEQ + j * 64 + row) * DIM + col0 + c * 8]);
      *reinterpret_cast<u16x8*>(&Ks[row * 72 + c * 8]) = v;
    }
    // stage V^T tile 64 d x 64 keys (b128, from global V^T)
#pragma unroll
    for (int i = 0; i < 2; i++) {
      int idx = tid + i * 256;
      int row = idx >> 3, c = idx & 7;   // row = d, c*8 = key chunk
      u16x8 v = *reinterpret_cast<const u16x8*>(&Vtg[(size_t)(col0 + row) * M_ROWS + bp * SEQ + j * 64 + c * 8]);
      *reinterpret_cast<u16x8*>(&Vs[row * 72 + c * 8]) = v;
    }
    __syncthreads();

    // S^T = K·Q^T : 4 key-tiles of 16; D row = key16 = quad*4+r, col = q = l15
    f32x4 st[4];
#pragma unroll
    for (int ct = 0; ct < 4; ct++) {
      f32x4 zacc = {};
#pragma unroll
      for (int kd = 0; kd < 2; kd++) {
        bf16x8 kf = *reinterpret_cast<const bf16x8*>(&Ks[(ct * 16 + l15) * 72 + kd * 32 + quad * 8]);
        zacc = __builtin_amdgcn_mfma_f32_16x16x32_bf16(kf, qf[kd], zacc, 0, 0, 0);
      }
      st[ct] = zacc * 0.125f;
    }

    // online softmax for column q=l15 over this tile's 64 keys (16/lane)
    float pm = -1e30f;
#pragma unroll
    for (int ct = 0; ct < 4; ct++)
#pragma unroll
      for (int r = 0; r < 4; r++) pm = fmaxf(pm, st[ct][r]);
    pm = fmaxf(pm, __shfl_xor(pm, 16));
    pm = fmaxf(pm, __shfl_xor(pm, 32));
    float mn = fmaxf(m_, pm);
    float alpha = __expf(m_ - mn);
    m_ = mn;
    float rs = 0.0f;
#pragma unroll
    for (int ct = 0; ct < 4; ct++)
#pragma unroll
      for (int r = 0; r < 4; r++) {
        float pv = __expf(st[ct][r] - mn);
        st[ct][r] = pv;
        rs += pv;
      }
    rs += __shfl_xor(rs, 16);
    rs += __shfl_xor(rs, 32);
    l_ = l_ * alpha + rs;
    // rescale O (O rows are q = quad*4+r; alpha lives at lane q)
#pragma unroll
    for (int r = 0; r < 4; r++) {
      float ar = __shfl(alpha, quad * 4 + r);
#pragma unroll
      for (int nt = 0; nt < 4; nt++) o[nt][r] *= ar;
    }

    // P^T (C-layout) -> Pq[q][key] with packed b64 stores
#pragma unroll
    for (int t = 0; t < 4; t++) {
      u16x4 pk;
#pragma unroll
      for (int e = 0; e < 4; e++) pk[e] = f2b(st[t][e]);
      *reinterpret_cast<u16x4*>(&Pq[w][l15 * 72 + t * 16 + quad * 4]) = pk;
    }
    __threadfence_block();   // order per-wave LDS write -> read

    // O += P·V : A = P[q=l15][key=quad*8+j], B = V[key][d] from Vs[d][key]
#pragma unroll
    for (int c = 0; c < 2; c++) {
      bf16x8 af = *reinterpret_cast<const bf16x8*>(&Pq[w][l15 * 72 + c * 32 + quad * 8]);
#pragma unroll
      for (int nt = 0; nt < 4; nt++) {
        bf16x8 bv = *reinterpret_cast<const bf16x8*>(&Vs[(nt * 16 + l15) * 72 + c * 32 + quad * 8]);
        o[nt] = __builtin_amdgcn_mfma_f32_16x16x32_bf16(af, bv, o[nt], 0, 0, 0);
      }
    }
  }

  // epilogue: normalize (l lives at lane q) and write bf16 [M,512]
  float inv = 1.0f / l_;
#pragma unroll
  for (int r = 0; r < 4; r++) {
    float lr = __shfl(inv, quad * 4 + r);
#pragma unroll
    for (int nt = 0; nt < 4; nt++)
      Ob[(qrow0 + w * 16 + quad * 4 + r) * DIM + col0 + nt * 16 + l15] = f2b(o[nt][r] * lr);
  }
}

// ---------------------------------------------------------------------------
// Kernel 3: output GEMM  out[M,512](fp32) = Ob(bf16) @ Wo (Bt) + bias
// ---------------------------------------------------------------------------
__global__ __launch_bounds__(256) void gemm_out(const u16* __restrict__ Ab,
                                                const u16* __restrict__ Bt,
                                                const float* __restrict__ bias,
                                                float* __restrict__ C) {
  __shared__ u16 As[128 * 40];
  __shared__ u16 Bs[128 * 40];
  const int tid = threadIdx.x;
  const int lane = tid & 63;
  const int w = tid >> 6;
  const int l15 = lane & 15;
  const int quad = lane >> 4;
  const int gm = blockIdx.y * 128;
  const int gn = blockIdx.x * 128;
  const int wr = (w >> 1) * 64, wc = (w & 1) * 64;

  f32x4 acc[4][4] = {};

  for (int k0 = 0; k0 < DIM; k0 += 32) {
    __syncthreads();
#pragma unroll
    for (int i = 0; i < 2; i++) {
      int idx = tid + i * 256;
      int row = idx >> 2, c = idx & 3;
      u16x8 av = *reinterpret_cast<const u16x8*>(&Ab[(gm + row) * DIM + k0 + c * 8]);
      *reinterpret_cast<u16x8*>(&As[row * 40 + c * 8]) = av;
    }
#pragma unroll
    for (int i = 0; i < 2; i++) {
      int idx = tid + i * 256;
      int nrow = idx >> 2, c = idx & 3;
      u16x8 bv = *reinterpret_cast<const u16x8*>(&Bt[(gn + nrow) * DIM + k0 + c * 8]);
      *reinterpret_cast<u16x8*>(&Bs[nrow * 40 + c * 8]) = bv;
    }
    __syncthreads();

    bf16x8 af[4], bf[4];
#pragma unroll
    for (int mt = 0; mt < 4; mt++)
      af[mt] = *reinterpret_cast<const bf16x8*>(&As[(wr + mt * 16 + l15) * 40 + quad * 8]);
#pragma unroll
    for (int nt = 0; nt < 4; nt++)
      bf[nt] = *reinterpret_cast<const bf16x8*>(&Bs[(wc + nt * 16 + l15) * 40 + quad * 8]);
#pragma unroll
    for (int mt = 0; mt < 4; mt++)
#pragma unroll
      for (int nt = 0; nt < 4; nt++)
        acc[mt][nt] = __builtin_amdgcn_mfma_f32_16x16x32_bf16(af[mt], bf[nt], acc[mt][nt], 0, 0, 0);
  }

#pragma unroll
  for (int mt = 0; mt < 4; mt++)
#pragma unroll
    for (int nt = 0; nt < 4; nt++) {
      float bcol = bias[gn + wc + nt * 16 + l15];
#pragma unroll
      for (int r = 0; r < 4; r++)
        C[(gm + wr + mt * 16 + quad * 4 + r) * DIM + gn + wc + nt * 16 + l15] = acc[mt][nt][r] + bcol;
    }
}

// ---------------------------------------------------------------------------
extern "C" void kernel_launch(void* const* d_in, const int* in_sizes, int n_in,
                              void* d_out, int out_size, void* d_ws, size_t ws_size,
                              hipStream_t stream) {
  const float* q_in  = (const float*)d_in[0];
  const float* kv_in = (const float*)d_in[1];
  const float* Wq    = (const float*)d_in[2];
  const float* Wk    = (const float*)d_in[3];
  const float* Wv    = (const float*)d_in[4];
  const float* Wo    = (const float*)d_in[5];
  const float* bo    = (const float*)d_in[6];
  float* out = (float*)d_out;

  u16* ws = (u16*)d_ws;
  u16* Wqt = ws;
  u16* Wkt = ws + 262144;
  u16* Wvt = ws + 524288;
  u16* Wot = ws + 786432;
  u16* Qb  = ws + 1048576;
  u16* Kb  = Qb + (size_t)M_ROWS * DIM;
  u16* Vtg = Kb + (size_t)M_ROWS * DIM;   // V^T: [512 inner][16384 rows]
  u16* Ob  = Vtg + (size_t)M_ROWS * DIM;

  wtrans<<<dim3(16, 16, 4), 256, 0, stream>>>(Wq, Wk, Wv, Wo, ws);
  gemm_qkv<<<dim3(4, 128, 3), 256, 0, stream>>>(q_in, kv_in, Wqt, Wkt, Wvt, Qb, Kb, Vtg);
  attn<<<dim3(2048), 256, 0, stream>>>(Qb, Kb, Vtg, Ob);
  gemm_out<<<dim3(4, 128), 256, 0, stream>>>(Ob, Wot, bo, out);
}

// Round 4
// 237.800 us; speedup vs baseline: 1.1815x; 1.0688x over previous
//
#include <hip/hip_runtime.h>

typedef unsigned short u16;
typedef u16  u16x8 __attribute__((ext_vector_type(8)));
typedef u16  u16x4 __attribute__((ext_vector_type(4)));
typedef float f32x4 __attribute__((ext_vector_type(4)));
typedef __bf16 bf16x8 __attribute__((ext_vector_type(8)));

#define SEQ   512
#define DIM   512
#define DHEAD 64
#define M_ROWS 16384   // 4*8*512

#define AS1 __attribute__((address_space(1)))
#define AS3 __attribute__((address_space(3)))
// async global->LDS, 16B per lane, LDS dest = wave-uniform base + lane*16
#define GLL16(gp, lp) __builtin_amdgcn_global_load_lds((const AS1 void*)(gp), (AS3 void*)(lp), 16, 0, 0)

__device__ __forceinline__ u16 f2b(float f) {
  unsigned int x = __builtin_bit_cast(unsigned int, f);
  return (u16)((x + 0x7fffu + ((x >> 16) & 1u)) >> 16);
}

// ---------------------------------------------------------------------------
// Kernel 0a: convert inputs fp32 -> bf16 (memory-bound pass)
// 8.39M elements per buffer; 2048 per block -> 4096 blocks in x.
// ---------------------------------------------------------------------------
__global__ __launch_bounds__(256) void convert_in(const float* __restrict__ q,
                                                  const float* __restrict__ kv,
                                                  u16* __restrict__ qb,
                                                  u16* __restrict__ kvb) {
  const float* src = blockIdx.y ? kv : q;
  u16* dst = blockIdx.y ? kvb : qb;
  size_t i = ((size_t)blockIdx.x * 256 + threadIdx.x) * 8;
  float4 a = *reinterpret_cast<const float4*>(&src[i]);
  float4 b = *reinterpret_cast<const float4*>(&src[i + 4]);
  u16x8 o;
  o[0] = f2b(a.x); o[1] = f2b(a.y); o[2] = f2b(a.z); o[3] = f2b(a.w);
  o[4] = f2b(b.x); o[5] = f2b(b.y); o[6] = f2b(b.z); o[7] = f2b(b.w);
  *reinterpret_cast<u16x8*>(&dst[i]) = o;
}

// ---------------------------------------------------------------------------
// Kernel 0b: transpose + convert weights fp32 [K,N] -> bf16 [N,K]
// ---------------------------------------------------------------------------
__global__ __launch_bounds__(256) void wtrans(const float* __restrict__ Wq,
                                              const float* __restrict__ Wk,
                                              const float* __restrict__ Wv,
                                              const float* __restrict__ Wo,
                                              u16* __restrict__ out) {
  __shared__ float tile[32][33];
  const int tid = threadIdx.x;
  const int tx = tid & 31, ty = tid >> 5;
  const int z = blockIdx.z;
  const float* W = (z == 0) ? Wq : (z == 1) ? Wk : (z == 2) ? Wv : Wo;
  const int n0 = blockIdx.x * 32;
  const int k0 = blockIdx.y * 32;
#pragma unroll
  for (int i = 0; i < 4; i++) {
    int r = ty + i * 8;
    tile[r][tx] = W[(k0 + r) * DIM + n0 + tx];
  }
  __syncthreads();
  u16* o = out + (size_t)z * DIM * DIM;
#pragma unroll
  for (int i = 0; i < 4; i++) {
    int r = ty + i * 8;
    o[(n0 + r) * DIM + k0 + tx] = f2b(tile[tx][r]);
  }
}

// ---------------------------------------------------------------------------
// Kernel 1: fused Q/K/V^T projection GEMM, all-bf16, m97-style staging.
//  z=0: Qb[M,512] = Qin_b @ Wq      (A=Qin_b, B=Wqt)
//  z=1: Kb[M,512] = KVin_b @ Wk     (A=KVin_b, B=Wkt)
//  z=2: Vt[512,M] = Wv^T . kv^T     (A=Wvt,   B=KVin_b)
// 128x128 tile, BK=32, 4 waves; LDS unpadded pitch-32 (global_load_lds order)
// ---------------------------------------------------------------------------
__global__ __launch_bounds__(256) void gemm_qkv(const u16* __restrict__ Qin,
                                                const u16* __restrict__ KVin,
                                                const u16* __restrict__ Wqt,
                                                const u16* __restrict__ Wkt,
                                                const u16* __restrict__ Wvt,
                                                u16* __restrict__ Qb,
                                                u16* __restrict__ Kb,
                                                u16* __restrict__ Vt) {
  __shared__ __attribute__((aligned(16))) u16 As[128 * 32];
  __shared__ __attribute__((aligned(16))) u16 Bs[128 * 32];
  const int tid = threadIdx.x;
  const int lane = tid & 63;
  const int w = tid >> 6;
  const int l15 = lane & 15;
  const int quad = lane >> 4;
  const int z = blockIdx.z;
  const int wr = (w >> 1) * 64, wc = (w & 1) * 64;
  const int srow = lane >> 2;        // staging: 4 lanes per 32-elem row
  const int scol = (lane & 3) * 8;

  int gm, gn;
  const u16 *A, *B;
  if (z < 2) {
    gm = blockIdx.y * 128; gn = blockIdx.x * 128;
    A = z ? KVin : Qin;  B = z ? Wkt : Wqt;
  } else {
    gm = blockIdx.x * 128; gn = blockIdx.y * 128;
    A = Wvt; B = KVin;
  }

  f32x4 acc[4][4] = {};

  for (int k0 = 0; k0 < DIM; k0 += 32) {
    __syncthreads();
    // wave w stages rows w*32 .. w*32+31 of both tiles (2 instrs each)
#pragma unroll
    for (int i = 0; i < 2; i++) {
      int r0 = w * 32 + i * 16;
      GLL16(&A[(size_t)(gm + r0 + srow) * DIM + k0 + scol], &As[r0 * 32]);
      GLL16(&B[(size_t)(gn + r0 + srow) * DIM + k0 + scol], &Bs[r0 * 32]);
    }
    __syncthreads();

    bf16x8 af[4], bfr[4];
#pragma unroll
    for (int mt = 0; mt < 4; mt++)
      af[mt] = *reinterpret_cast<const bf16x8*>(&As[(wr + mt * 16 + l15) * 32 + quad * 8]);
#pragma unroll
    for (int nt = 0; nt < 4; nt++)
      bfr[nt] = *reinterpret_cast<const bf16x8*>(&Bs[(wc + nt * 16 + l15) * 32 + quad * 8]);
#pragma unroll
    for (int mt = 0; mt < 4; mt++)
#pragma unroll
      for (int nt = 0; nt < 4; nt++)
        acc[mt][nt] = __builtin_amdgcn_mfma_f32_16x16x32_bf16(af[mt], bfr[nt], acc[mt][nt], 0, 0, 0);
  }

  if (z < 2) {
    u16* C = (z == 0) ? Qb : Kb;
#pragma unroll
    for (int mt = 0; mt < 4; mt++)
#pragma unroll
      for (int nt = 0; nt < 4; nt++)
#pragma unroll
        for (int r = 0; r < 4; r++)
          C[(gm + wr + mt * 16 + quad * 4 + r) * DIM + gn + wc + nt * 16 + l15] = f2b(acc[mt][nt][r]);
  } else {
#pragma unroll
    for (int mt = 0; mt < 4; mt++)
#pragma unroll
      for (int nt = 0; nt < 4; nt++)
#pragma unroll
        for (int r = 0; r < 4; r++)
          Vt[(size_t)(gm + wr + mt * 16 + quad * 4 + r) * M_ROWS + gn + wc + nt * 16 + l15] = f2b(acc[mt][nt][r]);
  }
}

// ---------------------------------------------------------------------------
// Kernel 2: flash attention (unchanged from R2).
// ---------------------------------------------------------------------------
__global__ __launch_bounds__(256) void attn(const u16* __restrict__ Qb,
                                            const u16* __restrict__ Kb,
                                            const u16* __restrict__ Vtg,
                                            u16* __restrict__ Ob) {
  __shared__ u16 Qs[64 * 72];
  __shared__ u16 Ks[64 * 72];
  __shared__ u16 Vs[64 * 72];
  __shared__ u16 Pq[4][16 * 72];

  const int tid = threadIdx.x;
  const int lane = tid & 63;
  const int w = tid >> 6;
  const int l15 = lane & 15;
  const int quad = lane >> 4;

  const int bid = blockIdx.x;
  const int qt = bid & 7;
  const int bhp = bid >> 3;
  const int h = bhp & 7;
  const int bp = bhp >> 3;
  const int qrow0 = bp * SEQ + qt * 64;
  const int col0 = h * DHEAD;

#pragma unroll
  for (int i = 0; i < 2; i++) {
    int idx = tid + i * 256;
    int row = idx >> 3, c = idx & 7;
    u16x8 v = *reinterpret_cast<const u16x8*>(&Qb[(qrow0 + row) * DIM + col0 + c * 8]);
    *reinterpret_cast<u16x8*>(&Qs[row * 72 + c * 8]) = v;
  }
  __syncthreads();

  bf16x8 qf[2];
#pragma unroll
  for (int kd = 0; kd < 2; kd++)
    qf[kd] = *reinterpret_cast<const bf16x8*>(&Qs[(w * 16 + l15) * 72 + kd * 32 + quad * 8]);

  float m_ = -1e30f, l_ = 0.0f;
  f32x4 o[4] = {};

  for (int j = 0; j < 8; j++) {
    __syncthreads();
#pragma unroll
    for (int i = 0; i < 2; i++) {
      int idx = tid + i * 256;
      int row = idx >> 3, c = idx & 7;
      u16x8 v = *reinterpret_cast<const u16x8*>(&Kb[(bp * SEQ + j * 64 + row) * DIM + col0 + c * 8]);
      *reinterpret_cast<u16x8*>(&Ks[row * 72 + c * 8]) = v;
    }
#pragma unroll
    for (int i = 0; i < 2; i++) {
      int idx = tid + i * 256;
      int row = idx >> 3, c = idx & 7;
      u16x8 v = *reinterpret_cast<const u16x8*>(&Vtg[(size_t)(col0 + row) * M_ROWS + bp * SEQ + j * 64 + c * 8]);
      *reinterpret_cast<u16x8*>(&Vs[row * 72 + c * 8]) = v;
    }
    __syncthreads();

    f32x4 st[4];
#pragma unroll
    for (int ct = 0; ct < 4; ct++) {
      f32x4 zacc = {};
#pragma unroll
      for (int kd = 0; kd < 2; kd++) {
        bf16x8 kf = *reinterpret_cast<const bf16x8*>(&Ks[(ct * 16 + l15) * 72 + kd * 32 + quad * 8]);
        zacc = __builtin_amdgcn_mfma_f32_16x16x32_bf16(kf, qf[kd], zacc, 0, 0, 0);
      }
      st[ct] = zacc * 0.125f;
    }

    float pm = -1e30f;
#pragma unroll
    for (int ct = 0; ct < 4; ct++)
#pragma unroll
      for (int r = 0; r < 4; r++) pm = fmaxf(pm, st[ct][r]);
    pm = fmaxf(pm, __shfl_xor(pm, 16));
    pm = fmaxf(pm, __shfl_xor(pm, 32));
    float mn = fmaxf(m_, pm);
    float alpha = __expf(m_ - mn);
    m_ = mn;
    float rs = 0.0f;
#pragma unroll
    for (int ct = 0; ct < 4; ct++)
#pragma unroll
      for (int r = 0; r < 4; r++) {
        float pv = __expf(st[ct][r] - mn);
        st[ct][r] = pv;
        rs += pv;
      }
    rs += __shfl_xor(rs, 16);
    rs += __shfl_xor(rs, 32);
    l_ = l_ * alpha + rs;
#pragma unroll
    for (int r = 0; r < 4; r++) {
      float ar = __shfl(alpha, quad * 4 + r);
#pragma unroll
      for (int nt = 0; nt < 4; nt++) o[nt][r] *= ar;
    }

#pragma unroll
    for (int t = 0; t < 4; t++) {
      u16x4 pk;
#pragma unroll
      for (int e = 0; e < 4; e++) pk[e] = f2b(st[t][e]);
      *reinterpret_cast<u16x4*>(&Pq[w][l15 * 72 + t * 16 + quad * 4]) = pk;
    }
    __threadfence_block();

#pragma unroll
    for (int c = 0; c < 2; c++) {
      bf16x8 af = *reinterpret_cast<const bf16x8*>(&Pq[w][l15 * 72 + c * 32 + quad * 8]);
#pragma unroll
      for (int nt = 0; nt < 4; nt++) {
        bf16x8 bv = *reinterpret_cast<const bf16x8*>(&Vs[(nt * 16 + l15) * 72 + c * 32 + quad * 8]);
        o[nt] = __builtin_amdgcn_mfma_f32_16x16x32_bf16(af, bv, o[nt], 0, 0, 0);
      }
    }
  }

  float inv = 1.0f / l_;
#pragma unroll
  for (int r = 0; r < 4; r++) {
    float lr = __shfl(inv, quad * 4 + r);
#pragma unroll
    for (int nt = 0; nt < 4; nt++)
      Ob[(qrow0 + w * 16 + quad * 4 + r) * DIM + col0 + nt * 16 + l15] = f2b(o[nt][r] * lr);
  }
}

// ---------------------------------------------------------------------------
// Kernel 3: output GEMM, m97-style staging; fp32 epilogue + bias.
// ---------------------------------------------------------------------------
__global__ __launch_bounds__(256) void gemm_out(const u16* __restrict__ Ab,
                                                const u16* __restrict__ Bt,
                                                const float* __restrict__ bias,
                                                float* __restrict__ C) {
  __shared__ __attribute__((aligned(16))) u16 As[128 * 32];
  __shared__ __attribute__((aligned(16))) u16 Bs[128 * 32];
  const int tid = threadIdx.x;
  const int lane = tid & 63;
  const int w = tid >> 6;
  const int l15 = lane & 15;
  const int quad = lane >> 4;
  const int gm = blockIdx.y * 128;
  const int gn = blockIdx.x * 128;
  const int wr = (w >> 1) * 64, wc = (w & 1) * 64;
  const int srow = lane >> 2;
  const int scol = (lane & 3) * 8;

  f32x4 acc[4][4] = {};

  for (int k0 = 0; k0 < DIM; k0 += 32) {
    __syncthreads();
#pragma unroll
    for (int i = 0; i < 2; i++) {
      int r0 = w * 32 + i * 16;
      GLL16(&Ab[(size_t)(gm + r0 + srow) * DIM + k0 + scol], &As[r0 * 32]);
      GLL16(&Bt[(size_t)(gn + r0 + srow) * DIM + k0 + scol], &Bs[r0 * 32]);
    }
    __syncthreads();

    bf16x8 af[4], bfr[4];
#pragma unroll
    for (int mt = 0; mt < 4; mt++)
      af[mt] = *reinterpret_cast<const bf16x8*>(&As[(wr + mt * 16 + l15) * 32 + quad * 8]);
#pragma unroll
    for (int nt = 0; nt < 4; nt++)
      bfr[nt] = *reinterpret_cast<const bf16x8*>(&Bs[(wc + nt * 16 + l15) * 32 + quad * 8]);
#pragma unroll
    for (int mt = 0; mt < 4; mt++)
#pragma unroll
      for (int nt = 0; nt < 4; nt++)
        acc[mt][nt] = __builtin_amdgcn_mfma_f32_16x16x32_bf16(af[mt], bfr[nt], acc[mt][nt], 0, 0, 0);
  }

#pragma unroll
  for (int mt = 0; mt < 4; mt++)
#pragma unroll
    for (int nt = 0; nt < 4; nt++) {
      float bcol = bias[gn + wc + nt * 16 + l15];
#pragma unroll
      for (int r = 0; r < 4; r++)
        C[(gm + wr + mt * 16 + quad * 4 + r) * DIM + gn + wc + nt * 16 + l15] = acc[mt][nt][r] + bcol;
    }
}

// ---------------------------------------------------------------------------
extern "C" void kernel_launch(void* const* d_in, const int* in_sizes, int n_in,
                              void* d_out, int out_size, void* d_ws, size_t ws_size,
                              hipStream_t stream) {
  const float* q_in  = (const float*)d_in[0];
  const float* kv_in = (const float*)d_in[1];
  const float* Wq    = (const float*)d_in[2];
  const float* Wk    = (const float*)d_in[3];
  const float* Wv    = (const float*)d_in[4];
  const float* Wo    = (const float*)d_in[5];
  const float* bo    = (const float*)d_in[6];
  float* out = (float*)d_out;

  u16* ws = (u16*)d_ws;
  u16* Wqt = ws;
  u16* Wkt = ws + 262144;
  u16* Wvt = ws + 524288;
  u16* Wot = ws + 786432;
  u16* Qb  = ws + 1048576;
  u16* Kb  = Qb + (size_t)M_ROWS * DIM;
  u16* Vtg = Kb + (size_t)M_ROWS * DIM;
  u16* Ob  = Vtg + (size_t)M_ROWS * DIM;
  // bf16 copies of the fp32 inputs live in d_out (dead before gemm_out writes it)
  u16* Qin_b  = (u16*)d_out;
  u16* KVin_b = Qin_b + (size_t)M_ROWS * DIM;

  convert_in<<<dim3(4096, 2), 256, 0, stream>>>(q_in, kv_in, Qin_b, KVin_b);
  wtrans<<<dim3(16, 16, 4), 256, 0, stream>>>(Wq, Wk, Wv, Wo, ws);
  gemm_qkv<<<dim3(4, 128, 3), 256, 0, stream>>>(Qin_b, KVin_b, Wqt, Wkt, Wvt, Qb, Kb, Vtg);
  attn<<<dim3(2048), 256, 0, stream>>>(Qb, Kb, Vtg, Ob);
  gemm_out<<<dim3(4, 128), 256, 0, stream>>>(Ob, Wot, bo, out);
}

// Round 5
// 233.545 us; speedup vs baseline: 1.2030x; 1.0182x over previous
//
#include <hip/hip_runtime.h>

typedef unsigned short u16;
typedef u16  u16x8 __attribute__((ext_vector_type(8)));
typedef u16  u16x4 __attribute__((ext_vector_type(4)));
typedef float f32x4 __attribute__((ext_vector_type(4)));
typedef __bf16 bf16x8 __attribute__((ext_vector_type(8)));

#define SEQ   512
#define DIM   512
#define DHEAD 64
#define M_ROWS 16384   // 4*8*512

#define AS1 __attribute__((address_space(1)))
#define AS3 __attribute__((address_space(3)))
// async global->LDS, 16B per lane, LDS dest = wave-uniform base + lane*16
#define GLL16(gp, lp) __builtin_amdgcn_global_load_lds((const AS1 void*)(gp), (AS3 void*)(lp), 16, 0, 0)

__device__ __forceinline__ u16 f2b(float f) {
  unsigned int x = __builtin_bit_cast(unsigned int, f);
  return (u16)((x + 0x7fffu + ((x >> 16) & 1u)) >> 16);
}

// ---------------------------------------------------------------------------
// Kernel 0a: convert inputs fp32 -> bf16 (memory-bound pass)
// ---------------------------------------------------------------------------
__global__ __launch_bounds__(256) void convert_in(const float* __restrict__ q,
                                                  const float* __restrict__ kv,
                                                  u16* __restrict__ qb,
                                                  u16* __restrict__ kvb) {
  const float* src = blockIdx.y ? kv : q;
  u16* dst = blockIdx.y ? kvb : qb;
  size_t i = ((size_t)blockIdx.x * 256 + threadIdx.x) * 8;
  float4 a = *reinterpret_cast<const float4*>(&src[i]);
  float4 b = *reinterpret_cast<const float4*>(&src[i + 4]);
  u16x8 o;
  o[0] = f2b(a.x); o[1] = f2b(a.y); o[2] = f2b(a.z); o[3] = f2b(a.w);
  o[4] = f2b(b.x); o[5] = f2b(b.y); o[6] = f2b(b.z); o[7] = f2b(b.w);
  *reinterpret_cast<u16x8*>(&dst[i]) = o;
}

// ---------------------------------------------------------------------------
// Kernel 0b: transpose + convert weights fp32 [K,N] -> bf16 [N,K]
// ---------------------------------------------------------------------------
__global__ __launch_bounds__(256) void wtrans(const float* __restrict__ Wq,
                                              const float* __restrict__ Wk,
                                              const float* __restrict__ Wv,
                                              const float* __restrict__ Wo,
                                              u16* __restrict__ out) {
  __shared__ float tile[32][33];
  const int tid = threadIdx.x;
  const int tx = tid & 31, ty = tid >> 5;
  const int z = blockIdx.z;
  const float* W = (z == 0) ? Wq : (z == 1) ? Wk : (z == 2) ? Wv : Wo;
  const int n0 = blockIdx.x * 32;
  const int k0 = blockIdx.y * 32;
#pragma unroll
  for (int i = 0; i < 4; i++) {
    int r = ty + i * 8;
    tile[r][tx] = W[(k0 + r) * DIM + n0 + tx];
  }
  __syncthreads();
  u16* o = out + (size_t)z * DIM * DIM;
#pragma unroll
  for (int i = 0; i < 4; i++) {
    int r = ty + i * 8;
    o[(n0 + r) * DIM + k0 + tx] = f2b(tile[tx][r]);
  }
}

// ---------------------------------------------------------------------------
// Kernel 1: fused Q/K/V^T projection GEMM, all-bf16, m97-style staging.
// ---------------------------------------------------------------------------
__global__ __launch_bounds__(256) void gemm_qkv(const u16* __restrict__ Qin,
                                                const u16* __restrict__ KVin,
                                                const u16* __restrict__ Wqt,
                                                const u16* __restrict__ Wkt,
                                                const u16* __restrict__ Wvt,
                                                u16* __restrict__ Qb,
                                                u16* __restrict__ Kb,
                                                u16* __restrict__ Vt) {
  __shared__ __attribute__((aligned(16))) u16 As[128 * 32];
  __shared__ __attribute__((aligned(16))) u16 Bs[128 * 32];
  const int tid = threadIdx.x;
  const int lane = tid & 63;
  const int w = tid >> 6;
  const int l15 = lane & 15;
  const int quad = lane >> 4;
  const int z = blockIdx.z;
  const int wr = (w >> 1) * 64, wc = (w & 1) * 64;
  const int srow = lane >> 2;
  const int scol = (lane & 3) * 8;

  int gm, gn;
  const u16 *A, *B;
  if (z < 2) {
    gm = blockIdx.y * 128; gn = blockIdx.x * 128;
    A = z ? KVin : Qin;  B = z ? Wkt : Wqt;
  } else {
    gm = blockIdx.x * 128; gn = blockIdx.y * 128;
    A = Wvt; B = KVin;
  }

  f32x4 acc[4][4] = {};

  for (int k0 = 0; k0 < DIM; k0 += 32) {
    __syncthreads();
#pragma unroll
    for (int i = 0; i < 2; i++) {
      int r0 = w * 32 + i * 16;
      GLL16(&A[(size_t)(gm + r0 + srow) * DIM + k0 + scol], &As[r0 * 32]);
      GLL16(&B[(size_t)(gn + r0 + srow) * DIM + k0 + scol], &Bs[r0 * 32]);
    }
    __syncthreads();

    bf16x8 af[4], bfr[4];
#pragma unroll
    for (int mt = 0; mt < 4; mt++)
      af[mt] = *reinterpret_cast<const bf16x8*>(&As[(wr + mt * 16 + l15) * 32 + quad * 8]);
#pragma unroll
    for (int nt = 0; nt < 4; nt++)
      bfr[nt] = *reinterpret_cast<const bf16x8*>(&Bs[(wc + nt * 16 + l15) * 32 + quad * 8]);
#pragma unroll
    for (int mt = 0; mt < 4; mt++)
#pragma unroll
      for (int nt = 0; nt < 4; nt++)
        acc[mt][nt] = __builtin_amdgcn_mfma_f32_16x16x32_bf16(af[mt], bfr[nt], acc[mt][nt], 0, 0, 0);
  }

  if (z < 2) {
    u16* C = (z == 0) ? Qb : Kb;
#pragma unroll
    for (int mt = 0; mt < 4; mt++)
#pragma unroll
      for (int nt = 0; nt < 4; nt++)
#pragma unroll
        for (int r = 0; r < 4; r++)
          C[(gm + wr + mt * 16 + quad * 4 + r) * DIM + gn + wc + nt * 16 + l15] = f2b(acc[mt][nt][r]);
  } else {
#pragma unroll
    for (int mt = 0; mt < 4; mt++)
#pragma unroll
      for (int nt = 0; nt < 4; nt++)
#pragma unroll
        for (int r = 0; r < 4; r++)
          Vt[(size_t)(gm + wr + mt * 16 + quad * 4 + r) * M_ROWS + gn + wc + nt * 16 + l15] = f2b(acc[mt][nt][r]);
  }
}

// ---------------------------------------------------------------------------
// Kernel 2: flash attention, rewritten.
// Block = (bp, h, 128 q-rows): grid 1024. 4 waves, each 32 q (2 groups of 16).
// K/V staged in 128-key tiles (4 iters) via global_load_lds into split-plane
// pitch-32 LDS (structural-min banks). Q frags load direct global->reg.
// S^T = K*Q^T (C-layout col=q); P via per-wave LDS (pitch 136).
// ---------------------------------------------------------------------------
__global__ __launch_bounds__(256) void attn(const u16* __restrict__ Qb,
                                            const u16* __restrict__ Kb,
                                            const u16* __restrict__ Vtg,
                                            u16* __restrict__ Ob) {
  __shared__ __attribute__((aligned(16))) u16 Ks[2 * 128 * 32];   // [kd-plane][key][32]
  __shared__ __attribute__((aligned(16))) u16 Vs[4 * 64 * 32];    // [key-plane][d][32]
  __shared__ __attribute__((aligned(16))) u16 Pq[4][16 * 136];    // per-wave P [q][key]

  const int tid = threadIdx.x;
  const int lane = tid & 63;
  const int w = tid >> 6;
  const int l15 = lane & 15;
  const int quad = lane >> 4;
  const int srow = lane >> 2;        // staging row within 16-row chunk
  const int scol = (lane & 3) * 8;   // staging col within 32-elem plane row

  const int bid = blockIdx.x;
  const int qt = bid & 3;            // 4 q-tiles of 128 rows
  const int bhp = bid >> 2;
  const int h = bhp & 7;
  const int bp = bhp >> 3;           // 0..31
  const int qrow0 = bp * SEQ + qt * 128;
  const int col0 = h * DHEAD;

  // Q fragments direct from global (B-operand layout: lane holds q=l15)
  bf16x8 qf[2][2];
#pragma unroll
  for (int g = 0; g < 2; g++)
#pragma unroll
    for (int kd = 0; kd < 2; kd++)
      qf[g][kd] = *reinterpret_cast<const bf16x8*>(
          &Qb[(size_t)(qrow0 + w * 32 + g * 16 + l15) * DIM + col0 + kd * 32 + quad * 8]);

  float m_[2] = {-1e30f, -1e30f}, l_[2] = {0.0f, 0.0f};
  f32x4 o[2][4] = {};

  for (int j = 0; j < 4; j++) {
    __syncthreads();
    const int krow0 = bp * SEQ + j * 128;
    // K staging: 16 GLL16 total (plane 0..1, chunk 0..7); wave w takes t=4w..4w+3
#pragma unroll
    for (int i = 0; i < 4; i++) {
      int t = w * 4 + i;
      int plane = t & 1, chunk = t >> 1;
      GLL16(&Kb[(size_t)(krow0 + chunk * 16 + srow) * DIM + col0 + plane * 32 + scol],
            &Ks[plane * 4096 + chunk * 512]);
    }
    // V staging: 16 GLL16 (plane 0..3 = key chunk, chunk 0..3 = d chunk)
#pragma unroll
    for (int i = 0; i < 4; i++) {
      int t = w * 4 + i;
      int plane = t & 3, chunk = t >> 2;
      GLL16(&Vtg[(size_t)(col0 + chunk * 16 + srow) * M_ROWS + krow0 + plane * 32 + scol],
            &Vs[plane * 2048 + chunk * 512]);
    }
    __syncthreads();

#pragma unroll
    for (int g = 0; g < 2; g++) {
      // S^T = K*Q^T : 8 key-tiles of 16; D[key][q=l15]
      f32x4 st[8];
#pragma unroll
      for (int ct = 0; ct < 8; ct++) {
        f32x4 z = {};
#pragma unroll
        for (int kd = 0; kd < 2; kd++) {
          bf16x8 kf = *reinterpret_cast<const bf16x8*>(&Ks[kd * 4096 + (ct * 16 + l15) * 32 + quad * 8]);
          z = __builtin_amdgcn_mfma_f32_16x16x32_bf16(kf, qf[g][kd], z, 0, 0, 0);
        }
        st[ct] = z * 0.125f;
      }

      // online softmax for q=l15 over 128 keys (32/lane, reduce across quads)
      float pm = -1e30f;
#pragma unroll
      for (int ct = 0; ct < 8; ct++)
#pragma unroll
        for (int r = 0; r < 4; r++) pm = fmaxf(pm, st[ct][r]);
      pm = fmaxf(pm, __shfl_xor(pm, 16));
      pm = fmaxf(pm, __shfl_xor(pm, 32));
      float mn = fmaxf(m_[g], pm);
      float alpha = __expf(m_[g] - mn);
      m_[g] = mn;
      float rs = 0.0f;
#pragma unroll
      for (int ct = 0; ct < 8; ct++)
#pragma unroll
        for (int r = 0; r < 4; r++) {
          float pv = __expf(st[ct][r] - mn);
          st[ct][r] = pv;
          rs += pv;
        }
      rs += __shfl_xor(rs, 16);
      rs += __shfl_xor(rs, 32);
      l_[g] = l_[g] * alpha + rs;
#pragma unroll
      for (int r = 0; r < 4; r++) {
        float ar = __shfl(alpha, quad * 4 + r);
#pragma unroll
        for (int nt = 0; nt < 4; nt++) o[g][nt][r] *= ar;
      }

      // P^T (C-layout) -> Pq[q][key], packed b64 stores
#pragma unroll
      for (int ct = 0; ct < 8; ct++) {
        u16x4 pk;
#pragma unroll
        for (int e = 0; e < 4; e++) pk[e] = f2b(st[ct][e]);
        *reinterpret_cast<u16x4*>(&Pq[w][l15 * 136 + ct * 16 + quad * 4]) = pk;
      }
      __threadfence_block();

      // O += P*V : A = Pq[q=l15][key], B = Vs plane c2 [d][key-chunk]
#pragma unroll
      for (int c2 = 0; c2 < 4; c2++) {
        bf16x8 af = *reinterpret_cast<const bf16x8*>(&Pq[w][l15 * 136 + c2 * 32 + quad * 8]);
#pragma unroll
        for (int nt = 0; nt < 4; nt++) {
          bf16x8 bv = *reinterpret_cast<const bf16x8*>(&Vs[c2 * 2048 + (nt * 16 + l15) * 32 + quad * 8]);
          o[g][nt] = __builtin_amdgcn_mfma_f32_16x16x32_bf16(af, bv, o[g][nt], 0, 0, 0);
        }
      }
      __threadfence_block();   // Pq reads done before next group overwrites
    }
  }

  // epilogue: normalize and write bf16 [M,512]
#pragma unroll
  for (int g = 0; g < 2; g++) {
    float inv = 1.0f / l_[g];
#pragma unroll
    for (int r = 0; r < 4; r++) {
      float lr = __shfl(inv, quad * 4 + r);
      int row = qrow0 + w * 32 + g * 16 + quad * 4 + r;
#pragma unroll
      for (int nt = 0; nt < 4; nt++)
        Ob[(size_t)row * DIM + col0 + nt * 16 + l15] = f2b(o[g][nt][r] * lr);
    }
  }
}

// ---------------------------------------------------------------------------
// Kernel 3: output GEMM, m97-style staging; fp32 epilogue + bias.
// ---------------------------------------------------------------------------
__global__ __launch_bounds__(256) void gemm_out(const u16* __restrict__ Ab,
                                                const u16* __restrict__ Bt,
                                                const float* __restrict__ bias,
                                                float* __restrict__ C) {
  __shared__ __attribute__((aligned(16))) u16 As[128 * 32];
  __shared__ __attribute__((aligned(16))) u16 Bs[128 * 32];
  const int tid = threadIdx.x;
  const int lane = tid & 63;
  const int w = tid >> 6;
  const int l15 = lane & 15;
  const int quad = lane >> 4;
  const int gm = blockIdx.y * 128;
  const int gn = blockIdx.x * 128;
  const int wr = (w >> 1) * 64, wc = (w & 1) * 64;
  const int srow = lane >> 2;
  const int scol = (lane & 3) * 8;

  f32x4 acc[4][4] = {};

  for (int k0 = 0; k0 < DIM; k0 += 32) {
    __syncthreads();
#pragma unroll
    for (int i = 0; i < 2; i++) {
      int r0 = w * 32 + i * 16;
      GLL16(&Ab[(size_t)(gm + r0 + srow) * DIM + k0 + scol], &As[r0 * 32]);
      GLL16(&Bt[(size_t)(gn + r0 + srow) * DIM + k0 + scol], &Bs[r0 * 32]);
    }
    __syncthreads();

    bf16x8 af[4], bfr[4];
#pragma unroll
    for (int mt = 0; mt < 4; mt++)
      af[mt] = *reinterpret_cast<const bf16x8*>(&As[(wr + mt * 16 + l15) * 32 + quad * 8]);
#pragma unroll
    for (int nt = 0; nt < 4; nt++)
      bfr[nt] = *reinterpret_cast<const bf16x8*>(&Bs[(wc + nt * 16 + l15) * 32 + quad * 8]);
#pragma unroll
    for (int mt = 0; mt < 4; mt++)
#pragma unroll
      for (int nt = 0; nt < 4; nt++)
        acc[mt][nt] = __builtin_amdgcn_mfma_f32_16x16x32_bf16(af[mt], bfr[nt], acc[mt][nt], 0, 0, 0);
  }

#pragma unroll
  for (int mt = 0; mt < 4; mt++)
#pragma unroll
    for (int nt = 0; nt < 4; nt++) {
      float bcol = bias[gn + wc + nt * 16 + l15];
#pragma unroll
      for (int r = 0; r < 4; r++)
        C[(gm + wr + mt * 16 + quad * 4 + r) * DIM + gn + wc + nt * 16 + l15] = acc[mt][nt][r] + bcol;
    }
}

// ---------------------------------------------------------------------------
extern "C" void kernel_launch(void* const* d_in, const int* in_sizes, int n_in,
                              void* d_out, int out_size, void* d_ws, size_t ws_size,
                              hipStream_t stream) {
  const float* q_in  = (const float*)d_in[0];
  const float* kv_in = (const float*)d_in[1];
  const float* Wq    = (const float*)d_in[2];
  const float* Wk    = (const float*)d_in[3];
  const float* Wv    = (const float*)d_in[4];
  const float* Wo    = (const float*)d_in[5];
  const float* bo    = (const float*)d_in[6];
  float* out = (float*)d_out;

  u16* ws = (u16*)d_ws;
  u16* Wqt = ws;
  u16* Wkt = ws + 262144;
  u16* Wvt = ws + 524288;
  u16* Wot = ws + 786432;
  u16* Qb  = ws + 1048576;
  u16* Kb  = Qb + (size_t)M_ROWS * DIM;
  u16* Vtg = Kb + (size_t)M_ROWS * DIM;
  u16* Ob  = Vtg + (size_t)M_ROWS * DIM;
  // bf16 copies of the fp32 inputs live in d_out (dead before gemm_out writes it)
  u16* Qin_b  = (u16*)d_out;
  u16* KVin_b = Qin_b + (size_t)M_ROWS * DIM;

  convert_in<<<dim3(4096, 2), 256, 0, stream>>>(q_in, kv_in, Qin_b, KVin_b);
  wtrans<<<dim3(16, 16, 4), 256, 0, stream>>>(Wq, Wk, Wv, Wo, ws);
  gemm_qkv<<<dim3(4, 128, 3), 256, 0, stream>>>(Qin_b, KVin_b, Wqt, Wkt, Wvt, Qb, Kb, Vtg);
  attn<<<dim3(1024), 256, 0, stream>>>(Qb, Kb, Vtg, Ob);
  gemm_out<<<dim3(4, 128), 256, 0, stream>>>(Ob, Wot, bo, out);
}

// Round 8
// 229.183 us; speedup vs baseline: 1.2259x; 1.0190x over previous
//
#include <hip/hip_runtime.h>

typedef unsigned short u16;
typedef unsigned int   u32;
typedef u16  u16x8 __attribute__((ext_vector_type(8)));
typedef u16  u16x4 __attribute__((ext_vector_type(4)));
typedef float f32x4 __attribute__((ext_vector_type(4)));
typedef __bf16 bf16x8 __attribute__((ext_vector_type(8)));

#define SEQ   512
#define DIM   512
#define DHEAD 64
#define M_ROWS 16384   // 4*8*512

#define AS1 __attribute__((address_space(1)))
#define AS3 __attribute__((address_space(3)))
// async global->LDS, 16B per lane, LDS dest = wave-uniform base + lane*16
#define GLL16(gp, lp) __builtin_amdgcn_global_load_lds((const AS1 void*)(gp), (AS3 void*)(lp), 16, 0, 0)

__device__ __forceinline__ u16 f2b(float f) {
  u32 x = __builtin_bit_cast(u32, f);
  return (u16)((x + 0x7fffu + ((x >> 16) & 1u)) >> 16);
}

// ---------------------------------------------------------------------------
// Kernel 0: prep = convert inputs fp32->bf16 (blocks 0..8191) + weight
// transpose fp32 [K,N] -> bf16 [N,K] (blocks 8192..9215). One launch.
// ---------------------------------------------------------------------------
__global__ __launch_bounds__(256) void prep(const float* __restrict__ q,
                                            const float* __restrict__ kv,
                                            const float* __restrict__ Wq,
                                            const float* __restrict__ Wk,
                                            const float* __restrict__ Wv,
                                            const float* __restrict__ Wo,
                                            u16* __restrict__ qb,
                                            u16* __restrict__ kvb,
                                            u16* __restrict__ wout) {
  __shared__ float tile[32][33];
  const int bid = blockIdx.x;
  if (bid < 8192) {
    const float* src = (bid >= 4096) ? kv : q;
    u16* dst = (bid >= 4096) ? kvb : qb;
    size_t i = ((size_t)(bid & 4095) * 256 + threadIdx.x) * 8;
    float4 a = *reinterpret_cast<const float4*>(&src[i]);
    float4 b = *reinterpret_cast<const float4*>(&src[i + 4]);
    u16x8 o;
    o[0] = f2b(a.x); o[1] = f2b(a.y); o[2] = f2b(a.z); o[3] = f2b(a.w);
    o[4] = f2b(b.x); o[5] = f2b(b.y); o[6] = f2b(b.z); o[7] = f2b(b.w);
    *reinterpret_cast<u16x8*>(&dst[i]) = o;
  } else {
    const int rem = bid - 8192;          // 0..1023
    const int z = rem >> 8;              // weight index 0..3
    const int t = rem & 255;
    const int n0 = (t & 15) * 32;
    const int k0 = (t >> 4) * 32;
    const int tid = threadIdx.x;
    const int tx = tid & 31, ty = tid >> 5;
    const float* W = (z == 0) ? Wq : (z == 1) ? Wk : (z == 2) ? Wv : Wo;
#pragma unroll
    for (int i = 0; i < 4; i++) {
      int r = ty + i * 8;
      tile[r][tx] = W[(k0 + r) * DIM + n0 + tx];
    }
    __syncthreads();
    u16* o = wout + (size_t)z * DIM * DIM;
#pragma unroll
    for (int i = 0; i < 4; i++) {
      int r = ty + i * 8;
      o[(n0 + r) * DIM + k0 + tx] = f2b(tile[tx][r]);
    }
  }
}

// ---------------------------------------------------------------------------
// Kernel 1: fused Q/K/V^T projection GEMM, all-bf16, GLL16 staging.
// 256x128 tile, BK=32, 4 waves in 2x2, each wave 128x64 (8x4 MFMA 16x16x32).
//  z=0: Qb[M,512] = Qin_b @ Wq     z=1: Kb = KVin_b @ Wk
//  z=2: Vt[512,M] = Wv^T . kv^T    (A=Wvt, B=KVin_b)
// NO scale folding — attn applies the 0.125 itself (known-good R5 semantics).
// ---------------------------------------------------------------------------
__global__ __launch_bounds__(256, 2) void gemm_qkv(const u16* __restrict__ Qin,
                                                   const u16* __restrict__ KVin,
                                                   const u16* __restrict__ Wqt,
                                                   const u16* __restrict__ Wkt,
                                                   const u16* __restrict__ Wvt,
                                                   u16* __restrict__ Qb,
                                                   u16* __restrict__ Kb,
                                                   u16* __restrict__ Vt) {
  __shared__ __attribute__((aligned(16))) u16 As[256 * 32];   // 16 KB
  __shared__ __attribute__((aligned(16))) u16 Bs[128 * 32];   // 8 KB
  const int tid = threadIdx.x;
  const int lane = tid & 63;
  const int w = tid >> 6;
  const int l15 = lane & 15;
  const int quad = lane >> 4;
  const int z = blockIdx.z;
  const int bid = blockIdx.x;          // 0..255
  const int wr = (w >> 1) * 128, wc = (w & 1) * 64;
  const int srow = lane >> 2;
  const int scol = (lane & 3) * 8;

  int gm, gn;
  const u16 *A, *B;
  if (z < 2) {
    gm = (bid >> 2) * 256;  gn = (bid & 3) * 128;     // 64 m-tiles x 4 n-tiles
    A = z ? KVin : Qin;  B = z ? Wkt : Wqt;
  } else {
    gm = (bid & 1) * 256;   gn = (bid >> 1) * 128;    // 2 m-tiles x 128 n-tiles
    A = Wvt; B = KVin;
  }

  f32x4 acc[8][4] = {};

  for (int k0 = 0; k0 < DIM; k0 += 32) {
    __syncthreads();
    // A: 256x32; wave w stages rows [w*64, w*64+64) -> 4 GLL16
#pragma unroll
    for (int i = 0; i < 4; i++) {
      int r0 = w * 64 + i * 16;
      GLL16(&A[(size_t)(gm + r0 + srow) * DIM + k0 + scol], &As[r0 * 32]);
    }
    // B: 128x32; wave w stages rows [w*32, w*32+32) -> 2 GLL16
#pragma unroll
    for (int i = 0; i < 2; i++) {
      int r0 = w * 32 + i * 16;
      GLL16(&B[(size_t)(gn + r0 + srow) * DIM + k0 + scol], &Bs[r0 * 32]);
    }
    __syncthreads();

    bf16x8 af[8], bfr[4];
#pragma unroll
    for (int mt = 0; mt < 8; mt++)
      af[mt] = *reinterpret_cast<const bf16x8*>(&As[(wr + mt * 16 + l15) * 32 + quad * 8]);
#pragma unroll
    for (int nt = 0; nt < 4; nt++)
      bfr[nt] = *reinterpret_cast<const bf16x8*>(&Bs[(wc + nt * 16 + l15) * 32 + quad * 8]);
#pragma unroll
    for (int mt = 0; mt < 8; mt++)
#pragma unroll
      for (int nt = 0; nt < 4; nt++)
        acc[mt][nt] = __builtin_amdgcn_mfma_f32_16x16x32_bf16(af[mt], bfr[nt], acc[mt][nt], 0, 0, 0);
  }

  if (z < 2) {
    u16* C = (z == 0) ? Qb : Kb;
#pragma unroll
    for (int mt = 0; mt < 8; mt++)
#pragma unroll
      for (int nt = 0; nt < 4; nt++)
#pragma unroll
        for (int r = 0; r < 4; r++)
          C[(size_t)(gm + wr + mt * 16 + quad * 4 + r) * DIM + gn + wc + nt * 16 + l15] = f2b(acc[mt][nt][r]);
  } else {
#pragma unroll
    for (int mt = 0; mt < 8; mt++)
#pragma unroll
      for (int nt = 0; nt < 4; nt++)
#pragma unroll
        for (int r = 0; r < 4; r++)
          Vt[(size_t)(gm + wr + mt * 16 + quad * 4 + r) * M_ROWS + gn + wc + nt * 16 + l15] = f2b(acc[mt][nt][r]);
  }
}

// ---------------------------------------------------------------------------
// Kernel 2: flash attention — VERBATIM last-known-good (R5, 233 µs pass).
// Block = (bp, h, 128 q-rows): grid 1024. 4 waves, each 32 q (2 groups of 16).
// 128-key tiles via global_load_lds into split-plane pitch-32 LDS.
// S^T = K*Q^T (C-layout col=q); scale 0.125 applied here; Pq double-fenced.
// ---------------------------------------------------------------------------
__global__ __launch_bounds__(256) void attn(const u16* __restrict__ Qb,
                                            const u16* __restrict__ Kb,
                                            const u16* __restrict__ Vtg,
                                            u16* __restrict__ Ob) {
  __shared__ __attribute__((aligned(16))) u16 Ks[2 * 128 * 32];   // [kd-plane][key][32]
  __shared__ __attribute__((aligned(16))) u16 Vs[4 * 64 * 32];    // [key-plane][d][32]
  __shared__ __attribute__((aligned(16))) u16 Pq[4][16 * 136];    // per-wave P [q][key]

  const int tid = threadIdx.x;
  const int lane = tid & 63;
  const int w = tid >> 6;
  const int l15 = lane & 15;
  const int quad = lane >> 4;
  const int srow = lane >> 2;
  const int scol = (lane & 3) * 8;

  const int bid = blockIdx.x;
  const int qt = bid & 3;            // 4 q-tiles of 128 rows
  const int bhp = bid >> 2;
  const int h = bhp & 7;
  const int bp = bhp >> 3;           // 0..31
  const int qrow0 = bp * SEQ + qt * 128;
  const int col0 = h * DHEAD;

  // Q fragments direct from global (B-operand layout: lane holds q=l15)
  bf16x8 qf[2][2];
#pragma unroll
  for (int g = 0; g < 2; g++)
#pragma unroll
    for (int kd = 0; kd < 2; kd++)
      qf[g][kd] = *reinterpret_cast<const bf16x8*>(
          &Qb[(size_t)(qrow0 + w * 32 + g * 16 + l15) * DIM + col0 + kd * 32 + quad * 8]);

  float m_[2] = {-1e30f, -1e30f}, l_[2] = {0.0f, 0.0f};
  f32x4 o[2][4] = {};

  for (int j = 0; j < 4; j++) {
    __syncthreads();
    const int krow0 = bp * SEQ + j * 128;
    // K staging: 16 GLL16 (plane=kd 0..1, chunk 0..7); wave w takes t=4w..4w+3
#pragma unroll
    for (int i = 0; i < 4; i++) {
      int t = w * 4 + i;
      int plane = t & 1, chunk = t >> 1;
      GLL16(&Kb[(size_t)(krow0 + chunk * 16 + srow) * DIM + col0 + plane * 32 + scol],
            &Ks[plane * 4096 + chunk * 512]);
    }
    // V staging: 16 GLL16 (plane=key-chunk 0..3, chunk=d-chunk 0..3)
#pragma unroll
    for (int i = 0; i < 4; i++) {
      int t = w * 4 + i;
      int plane = t & 3, chunk = t >> 2;
      GLL16(&Vtg[(size_t)(col0 + chunk * 16 + srow) * M_ROWS + krow0 + plane * 32 + scol],
            &Vs[plane * 2048 + chunk * 512]);
    }
    __syncthreads();

#pragma unroll
    for (int g = 0; g < 2; g++) {
      // S^T = K*Q^T : 8 key-tiles of 16; D[key][q=l15]
      f32x4 st[8];
#pragma unroll
      for (int ct = 0; ct < 8; ct++) {
        f32x4 z = {};
#pragma unroll
        for (int kd = 0; kd < 2; kd++) {
          bf16x8 kf = *reinterpret_cast<const bf16x8*>(&Ks[kd * 4096 + (ct * 16 + l15) * 32 + quad * 8]);
          z = __builtin_amdgcn_mfma_f32_16x16x32_bf16(kf, qf[g][kd], z, 0, 0, 0);
        }
        st[ct] = z * 0.125f;
      }

      // online softmax for q=l15 over 128 keys (32/lane, reduce across quads)
      float pm = -1e30f;
#pragma unroll
      for (int ct = 0; ct < 8; ct++)
#pragma unroll
        for (int r = 0; r < 4; r++) pm = fmaxf(pm, st[ct][r]);
      pm = fmaxf(pm, __shfl_xor(pm, 16));
      pm = fmaxf(pm, __shfl_xor(pm, 32));
      float mn = fmaxf(m_[g], pm);
      float alpha = __expf(m_[g] - mn);
      m_[g] = mn;
      float rs = 0.0f;
#pragma unroll
      for (int ct = 0; ct < 8; ct++)
#pragma unroll
        for (int r = 0; r < 4; r++) {
          float pv = __expf(st[ct][r] - mn);
          st[ct][r] = pv;
          rs += pv;
        }
      rs += __shfl_xor(rs, 16);
      rs += __shfl_xor(rs, 32);
      l_[g] = l_[g] * alpha + rs;
#pragma unroll
      for (int r = 0; r < 4; r++) {
        float ar = __shfl(alpha, quad * 4 + r);
#pragma unroll
        for (int nt = 0; nt < 4; nt++) o[g][nt][r] *= ar;
      }

      // P^T (C-layout) -> Pq[q][key], packed b64 stores
#pragma unroll
      for (int ct = 0; ct < 8; ct++) {
        u16x4 pk;
#pragma unroll
        for (int e = 0; e < 4; e++) pk[e] = f2b(st[ct][e]);
        *reinterpret_cast<u16x4*>(&Pq[w][l15 * 136 + ct * 16 + quad * 4]) = pk;
      }
      __threadfence_block();   // order Pq stores -> Pq reads

      // O += P*V : A = Pq[q=l15][key], B = Vs plane c2 [d][key-chunk]
#pragma unroll
      for (int c2 = 0; c2 < 4; c2++) {
        bf16x8 af = *reinterpret_cast<const bf16x8*>(&Pq[w][l15 * 136 + c2 * 32 + quad * 8]);
#pragma unroll
        for (int nt = 0; nt < 4; nt++) {
          bf16x8 bv = *reinterpret_cast<const bf16x8*>(&Vs[c2 * 2048 + (nt * 16 + l15) * 32 + quad * 8]);
          o[g][nt] = __builtin_amdgcn_mfma_f32_16x16x32_bf16(af, bv, o[g][nt], 0, 0, 0);
        }
      }
      __threadfence_block();   // order Pq reads -> next group's Pq stores
    }
  }

  // epilogue: normalize and write bf16 [M,512]
#pragma unroll
  for (int g = 0; g < 2; g++) {
    float inv = 1.0f / l_[g];
#pragma unroll
    for (int r = 0; r < 4; r++) {
      float lr = __shfl(inv, quad * 4 + r);
      int row = qrow0 + w * 32 + g * 16 + quad * 4 + r;
#pragma unroll
      for (int nt = 0; nt < 4; nt++)
        Ob[(size_t)row * DIM + col0 + nt * 16 + l15] = f2b(o[g][nt][r] * lr);
    }
  }
}

// ---------------------------------------------------------------------------
// Kernel 3: output GEMM, m97-style staging; fp32 epilogue + bias.
// ---------------------------------------------------------------------------
__global__ __launch_bounds__(256) void gemm_out(const u16* __restrict__ Ab,
                                                const u16* __restrict__ Bt,
                                                const float* __restrict__ bias,
                                                float* __restrict__ C) {
  __shared__ __attribute__((aligned(16))) u16 As[128 * 32];
  __shared__ __attribute__((aligned(16))) u16 Bs[128 * 32];
  const int tid = threadIdx.x;
  const int lane = tid & 63;
  const int w = tid >> 6;
  const int l15 = lane & 15;
  const int quad = lane >> 4;
  const int gm = blockIdx.y * 128;
  const int gn = blockIdx.x * 128;
  const int wr = (w >> 1) * 64, wc = (w & 1) * 64;
  const int srow = lane >> 2;
  const int scol = (lane & 3) * 8;

  f32x4 acc[4][4] = {};

  for (int k0 = 0; k0 < DIM; k0 += 32) {
    __syncthreads();
#pragma unroll
    for (int i = 0; i < 2; i++) {
      int r0 = w * 32 + i * 16;
      GLL16(&Ab[(size_t)(gm + r0 + srow) * DIM + k0 + scol], &As[r0 * 32]);
      GLL16(&Bt[(size_t)(gn + r0 + srow) * DIM + k0 + scol], &Bs[r0 * 32]);
    }
    __syncthreads();

    bf16x8 af[4], bfr[4];
#pragma unroll
    for (int mt = 0; mt < 4; mt++)
      af[mt] = *reinterpret_cast<const bf16x8*>(&As[(wr + mt * 16 + l15) * 32 + quad * 8]);
#pragma unroll
    for (int nt = 0; nt < 4; nt++)
      bfr[nt] = *reinterpret_cast<const bf16x8*>(&Bs[(wc + nt * 16 + l15) * 32 + quad * 8]);
#pragma unroll
    for (int mt = 0; mt < 4; mt++)
#pragma unroll
      for (int nt = 0; nt < 4; nt++)
        acc[mt][nt] = __builtin_amdgcn_mfma_f32_16x16x32_bf16(af[mt], bfr[nt], acc[mt][nt], 0, 0, 0);
  }

#pragma unroll
  for (int mt = 0; mt < 4; mt++)
#pragma unroll
    for (int nt = 0; nt < 4; nt++) {
      float bcol = bias[gn + wc + nt * 16 + l15];
#pragma unroll
      for (int r = 0; r < 4; r++)
        C[(size_t)(gm + wr + mt * 16 + quad * 4 + r) * DIM + gn + wc + nt * 16 + l15] = acc[mt][nt][r] + bcol;
    }
}

// ---------------------------------------------------------------------------
extern "C" void kernel_launch(void* const* d_in, const int* in_sizes, int n_in,
                              void* d_out, int out_size, void* d_ws, size_t ws_size,
                              hipStream_t stream) {
  const float* q_in  = (const float*)d_in[0];
  const float* kv_in = (const float*)d_in[1];
  const float* Wq    = (const float*)d_in[2];
  const float* Wk    = (const float*)d_in[3];
  const float* Wv    = (const float*)d_in[4];
  const float* Wo    = (const float*)d_in[5];
  const float* bo    = (const float*)d_in[6];
  float* out = (float*)d_out;

  u16* ws = (u16*)d_ws;
  u16* Wqt = ws;
  u16* Wkt = ws + 262144;
  u16* Wvt = ws + 524288;
  u16* Wot = ws + 786432;
  u16* Qb  = ws + 1048576;
  u16* Kb  = Qb + (size_t)M_ROWS * DIM;
  u16* Vtg = Kb + (size_t)M_ROWS * DIM;
  u16* Ob  = Vtg + (size_t)M_ROWS * DIM;
  // bf16 copies of the fp32 inputs live in d_out (dead before gemm_out writes it)
  u16* Qin_b  = (u16*)d_out;
  u16* KVin_b = Qin_b + (size_t)M_ROWS * DIM;

  prep<<<dim3(9216), 256, 0, stream>>>(q_in, kv_in, Wq, Wk, Wv, Wo, Qin_b, KVin_b, ws);
  gemm_qkv<<<dim3(256, 1, 3), 256, 0, stream>>>(Qin_b, KVin_b, Wqt, Wkt, Wvt, Qb, Kb, Vtg);
  attn<<<dim3(1024), 256, 0, stream>>>(Qb, Kb, Vtg, Ob);
  gemm_out<<<dim3(4, 128), 256, 0, stream>>>(Ob, Wot, bo, out);
}